// Round 2
// baseline (12625.517 us; speedup 1.0000x reference)
//
#include <hip/hip_runtime.h>
#include <stdint.h>

// LEM recurrent net, MI355X persistent-kernel implementation, round 2.
// Partition: NGRP=2 batch groups (128 rows) x CBLK=48 column-blocks (16 cols)
// = 96 blocks of 512 threads (8 waves), 1 block/CU, weights pinned in LDS.
// State exchange via MALL (agent-scope relaxed atomics, sc0sc1 cache bypass):
// NO buffer_wbl2 / buffer_inv in the loop. Barrier = per-block flag slots +
// wave-wide poll (no atomic contention).

#define NINP 128
#define NHID 768
#define NOUT 128
#define T_STEPS 256
#define BATCH 256

#define NGRP 2
#define CBLK 48
#define NBLK (NGRP * CBLK)      // 96 blocks
#define MROWS (BATCH / NGRP)    // 128 rows per group
#define NTHR 512
#define COLS 16                 // state columns per block
#define KH (NHID / 32)          // 24 K-iters for K=768
#define KI (NINP / 32)          // 4  K-iters for K=128

// LDS tile indices (each tile = 16 cols x 32 k bf16 = 1KB, fragment-major)
#define T_INP0 72               // after 3*24 W_hid tiles
#define T_WZ0  88               // after 4*4 W_inp tiles
#define NTILES 112              // 112 KB LDS

typedef short bf16x8 __attribute__((ext_vector_type(8)));
typedef float f32x4 __attribute__((ext_vector_type(4)));

__device__ __forceinline__ unsigned short f2b(float f) {
  union { float f; unsigned u; } x; x.f = f;
  return (unsigned short)((x.u + 0x7fffu + ((x.u >> 16) & 1u)) >> 16);  // RNE
}
__device__ __forceinline__ float b2f(unsigned short h) {
  union { unsigned u; float f; } x; x.u = ((unsigned)h) << 16; return x.f;
}
__device__ __forceinline__ float fsig(float x) { return 1.0f / (1.0f + __expf(-x)); }
__device__ __forceinline__ float ftanh(float x) {
  float e = __expf(2.0f * x);          // inf-safe: ->1 / ->-1 at extremes
  return 1.0f - 2.0f / (e + 1.0f);
}

#define MFMA16(a, b, c) __builtin_amdgcn_mfma_f32_16x16x32_bf16(a, b, c, 0, 0, 0)

#define AL64(p) __hip_atomic_load((const uint64_t*)(p), __ATOMIC_RELAXED, __HIP_MEMORY_SCOPE_AGENT)
#define AL32(p) __hip_atomic_load((const unsigned*)(p), __ATOMIC_RELAXED, __HIP_MEMORY_SCOPE_AGENT)
#define AS32(p, v) __hip_atomic_store((unsigned*)(p), (v), __ATOMIC_RELAXED, __HIP_MEMORY_SCOPE_AGENT)

// pack fp32 -> (bf16 hi << 16) | bf16 lo   (hi+lo ~ fp32-accurate operand)
__device__ __forceinline__ unsigned packf(float v) {
  unsigned short h = f2b(v);
  unsigned short l2 = f2b(v - b2f(h));
  return ((unsigned)h << 16) | (unsigned)l2;
}

// load 8 packed state words (32B, MALL-direct) -> hi/lo bf16x8 fragments
__device__ __forceinline__ void ld_state(const unsigned* p, bf16x8* hi, bf16x8* lo) {
  uint64_t q0 = AL64(p + 0);
  uint64_t q1 = AL64(p + 2);
  uint64_t q2 = AL64(p + 4);
  uint64_t q3 = AL64(p + 6);
  union { uint64_t q; unsigned u[2]; } a{q0}, b{q1}, c{q2}, d{q3};
  union { unsigned u[4]; bf16x8 v; } H, L;
  H.u[0] = (a.u[0] >> 16) | (a.u[1] & 0xffff0000u);
  L.u[0] = (a.u[0] & 0xffffu) | (a.u[1] << 16);
  H.u[1] = (b.u[0] >> 16) | (b.u[1] & 0xffff0000u);
  L.u[1] = (b.u[0] & 0xffffu) | (b.u[1] << 16);
  H.u[2] = (c.u[0] >> 16) | (c.u[1] & 0xffff0000u);
  L.u[2] = (c.u[0] & 0xffffu) | (c.u[1] << 16);
  H.u[3] = (d.u[0] >> 16) | (d.u[1] & 0xffff0000u);
  L.u[3] = (d.u[0] & 0xffffu) | (d.u[1] << 16);
  *hi = H.v; *lo = L.v;
}

// Split fp32 into hi/lo bf16 fragments (for x input and W_cls)
__device__ __forceinline__ void split8(const float* p, bf16x8* hi, bf16x8* lo) {
  union { bf16x8 v; unsigned short s[8]; } H, L;
#pragma unroll
  for (int e = 0; e < 8; ++e) {
    float v = p[e];
    unsigned short h = f2b(v);
    H.s[e] = h;
    L.s[e] = f2b(v - b2f(h));
  }
  *hi = H.v; *lo = L.v;
}

__global__ __launch_bounds__(NTHR, 1) void lem_kernel(
    const float* __restrict__ x,       // [T][B][NINP]
    const float* __restrict__ W_inp,   // [4*NHID][NINP]
    const float* __restrict__ b_inp,   // [4*NHID]
    const float* __restrict__ W_hid,   // [3*NHID][NHID]
    const float* __restrict__ b_hid,   // [3*NHID]
    const float* __restrict__ W_z,     // [NHID][NHID]
    const float* __restrict__ b_z,     // [NHID]
    const float* __restrict__ W_cls,   // [NOUT][NHID]
    const float* __restrict__ b_cls,   // [NOUT]
    float* __restrict__ out,           // [B][NOUT]
    unsigned* __restrict__ Y,          // packed hi|lo state [B][NHID]
    unsigned* __restrict__ Z,          // packed hi|lo state [B][NHID]
    unsigned* __restrict__ flags)      // NGRP * 64 flag slots
{
  __shared__ unsigned short wlds[NTILES * 512];  // 112 KB

  const int tid = threadIdx.x;
  const int l   = tid & 63;
  const int w   = tid >> 6;            // wave 0..7 -> 16-row tile
  const int g   = blockIdx.x / CBLK;
  const int c   = blockIdx.x % CBLK;
  const int colbase = c * COLS;
  const int lc  = l & 15;              // A row-in-tile / B col-in-tile
  const int kg8 = (l >> 4) * 8;        // k-group offset

  // ---- one-time: load + pack weight slices into LDS (bf16, fragment-major)
  for (int idx = tid; idx < NTILES * 512; idx += NTHR) {
    int t = idx >> 9;
    int r = idx & 511;
    int ll = r >> 3;
    int e  = r & 7;
    int col16 = ll & 15;
    int kk = ((ll >> 4) * 8) + e;
    float v;
    if (t < T_INP0) {                      // W_hid: t = seg*24 + kt
      int seg = t / 24, kt = t % 24;
      v = W_hid[(size_t)(seg * NHID + colbase + col16) * NHID + kt * 32 + kk];
    } else if (t < T_WZ0) {                // W_inp: t-72 = seg*4 + kt
      int u = t - T_INP0; int seg = u >> 2, kt = u & 3;
      v = W_inp[(size_t)(seg * NHID + colbase + col16) * NINP + kt * 32 + kk];
    } else {                               // W_z: kt = t-88
      int kt = t - T_WZ0;
      v = W_z[(size_t)(colbase + col16) * NHID + kt * 32 + kk];
    }
    wlds[idx] = f2b(v);
  }
  __syncthreads();

#define LDSB(t) (*(const bf16x8*)&wlds[((t) << 9) + (l << 3)])

  // per-lane fixed indices / biases (fp32, exact)
  const int col  = colbase + lc;                // this lane's state column
  const int rowA = g * MROWS + w * 16 + lc;     // A-fragment row (batch)
  const int rowD = g * MROWS + w * 16 + (l >> 4) * 4;  // D rows rowD..rowD+3
  const float c1 = b_inp[col] + b_hid[col];                       // dt1
  const float c2 = b_inp[NHID + col] + b_hid[NHID + col];         // dt2
  const float cy = b_inp[3 * NHID + col] + b_hid[2 * NHID + col]; // y gate
  const float cz = b_inp[2 * NHID + col] + b_z[col];              // i_z + b_z
  unsigned* gflags = flags + g * 64;

  // input-projection accumulators for step 0
  f32x4 ai0{0,0,0,0}, ai1{0,0,0,0}, ai2{0,0,0,0}, ai3{0,0,0,0};
  {
    const float* xp0 = x + (size_t)rowA * NINP;
#pragma unroll
    for (int kt = 0; kt < KI; ++kt) {
      bf16x8 ah, al;
      split8(xp0 + kt * 32 + kg8, &ah, &al);
      ai0 = MFMA16(ah, LDSB(T_INP0 + 0 * 4 + kt), ai0);
      ai0 = MFMA16(al, LDSB(T_INP0 + 0 * 4 + kt), ai0);
      ai1 = MFMA16(ah, LDSB(T_INP0 + 1 * 4 + kt), ai1);
      ai1 = MFMA16(al, LDSB(T_INP0 + 1 * 4 + kt), ai1);
      ai2 = MFMA16(ah, LDSB(T_INP0 + 2 * 4 + kt), ai2);
      ai2 = MFMA16(al, LDSB(T_INP0 + 2 * 4 + kt), ai2);
      ai3 = MFMA16(ah, LDSB(T_INP0 + 3 * 4 + kt), ai3);
      ai3 = MFMA16(al, LDSB(T_INP0 + 3 * 4 + kt), ai3);
    }
  }

  f32x4 yloc{0,0,0,0}, zloc{0,0,0,0}, msb{0,0,0,0};

  for (int s = 0; s < T_STEPS; ++s) {
    const unsigned pa = 2 * s + 1, pb = 2 * s + 2;

    // ---------- phase A: hid = y @ W_hid^T (hi/lo A), z update ----------
    f32x4 h0{0,0,0,0}, h1{0,0,0,0}, h2{0,0,0,0};
    {
      const unsigned* yp = Y + (size_t)rowA * NHID + kg8;
#pragma unroll 4
      for (int kt = 0; kt < KH; ++kt) {
        bf16x8 ah, al;
        ld_state(yp + kt * 32, &ah, &al);
        bf16x8 bb0 = LDSB(0 * KH + kt);
        bf16x8 bb1 = LDSB(1 * KH + kt);
        bf16x8 bb2 = LDSB(2 * KH + kt);
        h0 = MFMA16(ah, bb0, h0); h0 = MFMA16(al, bb0, h0);
        h1 = MFMA16(ah, bb1, h1); h1 = MFMA16(al, bb1, h1);
        h2 = MFMA16(ah, bb2, h2); h2 = MFMA16(al, bb2, h2);
      }
    }
#pragma unroll
    for (int i = 0; i < 4; ++i) {
      float a1 = fsig(ai0[i] + h0[i] + c1);          // ms_dt_bar
      float a2 = fsig(ai1[i] + h1[i] + c2);          // ms_dt
      float gg = ftanh(ai3[i] + h2[i] + cy);
      float zn = (1.0f - a2) * zloc[i] + a2 * gg;
      zloc[i] = zn;
      msb[i] = a1;
      AS32(&Z[(size_t)(rowD + i) * NHID + col], packf(zn));
    }
    // arrive A: syncthreads drains vmcnt (stores at MALL), then flag store
    __syncthreads();
    if (tid == 0) AS32(&gflags[c], pa);

    // overlap barrier latency: input projection for step s+1
    f32x4 ni0{0,0,0,0}, ni1{0,0,0,0}, ni2{0,0,0,0}, ni3{0,0,0,0};
    if (s + 1 < T_STEPS) {
      const float* xp = x + ((size_t)(s + 1) * BATCH + rowA) * NINP;
#pragma unroll
      for (int kt = 0; kt < KI; ++kt) {
        bf16x8 ah, al;
        split8(xp + kt * 32 + kg8, &ah, &al);
        ni0 = MFMA16(ah, LDSB(T_INP0 + 0 * 4 + kt), ni0);
        ni0 = MFMA16(al, LDSB(T_INP0 + 0 * 4 + kt), ni0);
        ni1 = MFMA16(ah, LDSB(T_INP0 + 1 * 4 + kt), ni1);
        ni1 = MFMA16(al, LDSB(T_INP0 + 1 * 4 + kt), ni1);
        ni2 = MFMA16(ah, LDSB(T_INP0 + 2 * 4 + kt), ni2);
        ni2 = MFMA16(al, LDSB(T_INP0 + 2 * 4 + kt), ni2);
        ni3 = MFMA16(ah, LDSB(T_INP0 + 3 * 4 + kt), ni3);
        ni3 = MFMA16(al, LDSB(T_INP0 + 3 * 4 + kt), ni3);
      }
    }
    // wait A: wave 0 polls all group flags (contention-free), others s_barrier
    if (w == 0) {
      const unsigned* fp = gflags + (l < CBLK ? l : 0);
      while (true) {
        unsigned v = AL32(fp);
        if (__all((l >= CBLK) || (v >= pa))) break;
        __builtin_amdgcn_s_sleep(1);
      }
    }
    __syncthreads();

    // ---------- phase B: zWz = z @ W_z^T, y update ----------
    f32x4 az0{0,0,0,0}, az1{0,0,0,0};
    {
      const unsigned* zp = Z + (size_t)rowA * NHID + kg8;
#pragma unroll 4
      for (int kt = 0; kt < KH; kt += 2) {
        bf16x8 ah0, al0, ah1, al1;
        ld_state(zp + kt * 32, &ah0, &al0);
        ld_state(zp + (kt + 1) * 32, &ah1, &al1);
        bf16x8 bb0 = LDSB(T_WZ0 + kt);
        bf16x8 bb1 = LDSB(T_WZ0 + kt + 1);
        az0 = MFMA16(ah0, bb0, az0); az0 = MFMA16(al0, bb0, az0);
        az1 = MFMA16(ah1, bb1, az1); az1 = MFMA16(al1, bb1, az1);
      }
    }
#pragma unroll
    for (int i = 0; i < 4; ++i) {
      float tt = ftanh(az0[i] + az1[i] + ai2[i] + cz);
      float yn = (1.0f - msb[i]) * yloc[i] + msb[i] * tt;
      yloc[i] = yn;
      AS32(&Y[(size_t)(rowD + i) * NHID + col], packf(yn));
    }
    // arrive B + wait B
    __syncthreads();
    if (tid == 0) AS32(&gflags[c], pb);
    if (w == 0) {
      const unsigned* fp = gflags + (l < CBLK ? l : 0);
      while (true) {
        unsigned v = AL32(fp);
        if (__all((l >= CBLK) || (v >= pb))) break;
        __builtin_amdgcn_s_sleep(1);
      }
    }
    __syncthreads();

    ai0 = ni0; ai1 = ni1; ai2 = ni2; ai3 = ni3;
  }

  // ---------- epilogue: out = y @ W_cls^T + b_cls (blocks c<8) ----------
  if (c < 8) {
    f32x4 ao0{0,0,0,0}, ao1{0,0,0,0};
    const unsigned* yp = Y + (size_t)rowA * NHID + kg8;
    for (int kt = 0; kt < KH; kt += 2) {
      {
        const float* wp = W_cls + (size_t)(colbase + lc) * NHID + kt * 32 + kg8;
        bf16x8 bh, bl, ah, al;
        split8(wp, &bh, &bl);
        ld_state(yp + kt * 32, &ah, &al);
        ao0 = MFMA16(ah, bh, ao0); ao0 = MFMA16(al, bh, ao0);
      }
      {
        const float* wp = W_cls + (size_t)(colbase + lc) * NHID + (kt + 1) * 32 + kg8;
        bf16x8 bh, bl, ah, al;
        split8(wp, &bh, &bl);
        ld_state(yp + (kt + 1) * 32, &ah, &al);
        ao1 = MFMA16(ah, bh, ao1); ao1 = MFMA16(al, bh, ao1);
      }
    }
    float bc = b_cls[colbase + lc];
#pragma unroll
    for (int i = 0; i < 4; ++i)
      out[(size_t)(rowD + i) * NOUT + colbase + lc] = ao0[i] + ao1[i] + bc;
  }
}

extern "C" void kernel_launch(void* const* d_in, const int* in_sizes, int n_in,
                              void* d_out, int out_size, void* d_ws, size_t ws_size,
                              hipStream_t stream) {
  (void)in_sizes; (void)n_in; (void)out_size; (void)ws_size;
  const float* x     = (const float*)d_in[0];
  const float* W_inp = (const float*)d_in[1];
  const float* b_inp = (const float*)d_in[2];
  const float* W_hid = (const float*)d_in[3];
  const float* b_hid = (const float*)d_in[4];
  const float* W_z   = (const float*)d_in[5];
  const float* b_z   = (const float*)d_in[6];
  const float* W_cls = (const float*)d_in[7];
  const float* b_cls = (const float*)d_in[8];

  // workspace layout: Y (768KB), Z (768KB), flags (NGRP*64 u32)
  const size_t SB = (size_t)BATCH * NHID;  // 196608 words
  unsigned* Y = (unsigned*)d_ws;
  unsigned* Z = Y + SB;
  unsigned* flags = Z + SB;

  // zero initial state (y0=z0=0, packed 0) and flags, every call
  hipMemsetAsync(d_ws, 0, (2 * SB + NGRP * 64) * sizeof(unsigned), stream);

  lem_kernel<<<dim3(NBLK), dim3(NTHR), 0, stream>>>(
      x, W_inp, b_inp, W_hid, b_hid, W_z, b_z, W_cls, b_cls,
      (float*)d_out, Y, Z, flags);
}

// Round 3
// 3295.753 us; speedup vs baseline: 3.8308x; 3.8308x over previous
//
#include <hip/hip_runtime.h>
#include <stdint.h>

// LEM recurrent net, MI355X persistent-kernel implementation, round 3.
// NGRP=4 batch groups (64 rows) x CBLK=48 column-blocks (16 cols) = 192
// blocks x 256 thr, 1 block/CU, weights pinned in LDS.
// State exchange: fragment-ordered layout [kt][rt][kg][r16][e] so a wave's
// MFMA A-fragment load is one contiguous 2KB block; uncached (sc0 sc1)
// dwordx4 inline-asm loads, 3-deep software pipeline with counted vmcnt.
// Barrier: per-block flag in its own 64B line (plain store, no RMW),
// wave0 polls 48 flags with one vector load. No wbl2/inv anywhere.

#define NINP 128
#define NHID 768
#define NOUT 128
#define T_STEPS 256
#define BATCH 256

#define NGRP 4
#define CBLK 48
#define NBLK (NGRP * CBLK)      // 192 blocks
#define NTHR 256
#define KH 24                   // K-chunks of 32 for K=768
#define KI 4                    // K-chunks for K=128

// LDS tile indices (tile = 16 cols x 32 k bf16 = 1KB, fragment-major)
#define T_INP0 72               // after 3*24 W_hid tiles
#define T_WZ0  88               // after 4*4 W_inp tiles
#define NTILES 112              // 112 KB LDS

// state layout [kt:24][rt:16][kg:4][r16:16][e:8] u32; chunk stride in u32:
#define CHS 8192                // 16*4*16*8
#define SBUF 196608             // u32 per state buffer (768KB)

typedef short bf16x8 __attribute__((ext_vector_type(8)));
typedef float f32x4 __attribute__((ext_vector_type(4)));
typedef unsigned uint32x4 __attribute__((ext_vector_type(4)));

__device__ __forceinline__ unsigned short f2b(float f) {
  union { float f; unsigned u; } x; x.f = f;
  return (unsigned short)((x.u + 0x7fffu + ((x.u >> 16) & 1u)) >> 16);  // RNE
}
__device__ __forceinline__ float b2f(unsigned short h) {
  union { unsigned u; float f; } x; x.u = ((unsigned)h) << 16; return x.f;
}
__device__ __forceinline__ float fsig(float x) { return 1.0f / (1.0f + __expf(-x)); }
__device__ __forceinline__ float ftanh(float x) {
  float e = __expf(2.0f * x);
  return 1.0f - 2.0f / (e + 1.0f);
}

#define MFMA16(a, b, c) __builtin_amdgcn_mfma_f32_16x16x32_bf16(a, b, c, 0, 0, 0)

#define AL32(p) __hip_atomic_load((const unsigned*)(p), __ATOMIC_RELAXED, __HIP_MEMORY_SCOPE_AGENT)
#define AS32(p, v) __hip_atomic_store((unsigned*)(p), (v), __ATOMIC_RELAXED, __HIP_MEMORY_SCOPE_AGENT)

// uncached (device-coherent) 16B load, asm so we control vmcnt batching
__device__ __forceinline__ void uld16(uint32x4* dst, const unsigned* addr) {
  asm volatile("global_load_dwordx4 %0, %1, off sc0 sc1"
               : "=v"(*dst) : "v"(addr));
}
#define WAITV(N) do { \
  asm volatile("s_waitcnt vmcnt(" #N ")" ::: "memory"); \
  __builtin_amdgcn_sched_barrier(0); } while (0)

__device__ __forceinline__ unsigned packf(float v) {
  unsigned short h = f2b(v);
  unsigned short l2 = f2b(v - b2f(h));
  return ((unsigned)h << 16) | (unsigned)l2;
}

// 8 packed u32 (2 dwordx4) -> hi/lo bf16x8 fragments
__device__ __forceinline__ void unpack8(uint32x4 q0, uint32x4 q1,
                                        bf16x8* hi, bf16x8* lo) {
  union { unsigned u[4]; bf16x8 v; } H, L;
  H.u[0] = (q0.x >> 16) | (q0.y & 0xffff0000u);
  L.u[0] = (q0.x & 0xffffu) | (q0.y << 16);
  H.u[1] = (q0.z >> 16) | (q0.w & 0xffff0000u);
  L.u[1] = (q0.z & 0xffffu) | (q0.w << 16);
  H.u[2] = (q1.x >> 16) | (q1.y & 0xffff0000u);
  L.u[2] = (q1.x & 0xffffu) | (q1.y << 16);
  H.u[3] = (q1.z >> 16) | (q1.w & 0xffff0000u);
  L.u[3] = (q1.z & 0xffffu) | (q1.w << 16);
  *hi = H.v; *lo = L.v;
}

// fp32 -> hi/lo bf16 fragments (x input, W_cls)
__device__ __forceinline__ void split8(const float* p, bf16x8* hi, bf16x8* lo) {
  union { bf16x8 v; unsigned short s[8]; } H, L;
#pragma unroll
  for (int e = 0; e < 8; ++e) {
    float v = p[e];
    unsigned short h = f2b(v);
    H.s[e] = h;
    L.s[e] = f2b(v - b2f(h));
  }
  *hi = H.v; *lo = L.v;
}

__global__ __launch_bounds__(NTHR, 1) void lem_kernel(
    const float* __restrict__ x,       // [T][B][NINP]
    const float* __restrict__ W_inp,   // [4*NHID][NINP]
    const float* __restrict__ b_inp,   // [4*NHID]
    const float* __restrict__ W_hid,   // [3*NHID][NHID]
    const float* __restrict__ b_hid,   // [3*NHID]
    const float* __restrict__ W_z,     // [NHID][NHID]
    const float* __restrict__ b_z,     // [NHID]
    const float* __restrict__ W_cls,   // [NOUT][NHID]
    const float* __restrict__ b_cls,   // [NOUT]
    float* __restrict__ out,           // [B][NOUT]
    unsigned* __restrict__ Y,          // packed hi|lo, fragment-ordered
    unsigned* __restrict__ Z,
    unsigned* __restrict__ flags)      // per group: flagA[48*16], flagB[48*16]
{
  __shared__ unsigned short wlds[NTILES * 512];  // 112 KB

  const int tid = threadIdx.x;
  const int l   = tid & 63;
  const int w   = tid >> 6;            // wave 0..3
  const int g   = blockIdx.x / CBLK;
  const int c   = blockIdx.x % CBLK;
  const int colbase = c * 16;
  const int lc  = l & 15;
  const int kg8 = (l >> 4) * 8;

  // ---- one-time: pack weight slices into LDS (bf16, fragment-major) ----
  for (int idx = tid; idx < NTILES * 512; idx += NTHR) {
    int t = idx >> 9;
    int r = idx & 511;
    int ll = r >> 3;
    int e  = r & 7;
    int col16 = ll & 15;
    int kk = ((ll >> 4) * 8) + e;
    float v;
    if (t < T_INP0) {                      // W_hid
      int seg = t / 24, kt = t % 24;
      v = W_hid[(size_t)(seg * NHID + colbase + col16) * NHID + kt * 32 + kk];
    } else if (t < T_WZ0) {                // W_inp
      int u = t - T_INP0; int seg = u >> 2, kt = u & 3;
      v = W_inp[(size_t)(seg * NHID + colbase + col16) * NINP + kt * 32 + kk];
    } else {                               // W_z
      int kt = t - T_WZ0;
      v = W_z[(size_t)(colbase + col16) * NHID + kt * 32 + kk];
    }
    wlds[idx] = f2b(v);
  }
  __syncthreads();

#define LDSB(t) (*(const bf16x8*)&wlds[((t) << 9) + (l << 3)])

  const int col  = colbase + lc;
  const int rt   = 4 * g + w;                   // row tile (16 rows)
  const int rowA = rt * 16 + lc;                // A-fragment row
  const int rowD = rt * 16 + (l >> 4) * 4;      // D rows rowD..rowD+3
  const int rtl  = rt * 512 + (l >> 4) * 128 + lc * 8;  // per-lane load base
  const float c1 = b_inp[col] + b_hid[col];
  const float c2 = b_inp[NHID + col] + b_hid[NHID + col];
  const float cy = b_inp[3 * NHID + col] + b_hid[2 * NHID + col];
  const float cz = b_inp[2 * NHID + col] + b_z[col];
  // store addressing (fragment-ordered)
  const int kts = col >> 5, kgs = (col >> 3) & 3, es = col & 7;
  const int r16b = (l >> 4) * 4;
  unsigned* zs = Z + ((kts * 16 + rt) * 4 + kgs) * 128 + es;
  unsigned* ys = Y + ((kts * 16 + rt) * 4 + kgs) * 128 + es;
  unsigned* gfA = flags + g * 1536;
  unsigned* gfB = gfA + 768;

  // input projection for step 0 (cached loads; x is read-only)
  f32x4 ai0{0,0,0,0}, ai1{0,0,0,0}, ai2{0,0,0,0}, ai3{0,0,0,0};
  {
    const float* xp0 = x + (size_t)rowA * NINP;
#pragma unroll
    for (int kt = 0; kt < KI; ++kt) {
      bf16x8 ah, al;
      split8(xp0 + kt * 32 + kg8, &ah, &al);
      ai0 = MFMA16(ah, LDSB(T_INP0 + 0 * 4 + kt), ai0);
      ai0 = MFMA16(al, LDSB(T_INP0 + 0 * 4 + kt), ai0);
      ai1 = MFMA16(ah, LDSB(T_INP0 + 1 * 4 + kt), ai1);
      ai1 = MFMA16(al, LDSB(T_INP0 + 1 * 4 + kt), ai1);
      ai2 = MFMA16(ah, LDSB(T_INP0 + 2 * 4 + kt), ai2);
      ai2 = MFMA16(al, LDSB(T_INP0 + 2 * 4 + kt), ai2);
      ai3 = MFMA16(ah, LDSB(T_INP0 + 3 * 4 + kt), ai3);
      ai3 = MFMA16(al, LDSB(T_INP0 + 3 * 4 + kt), ai3);
    }
  }

  f32x4 yloc{0,0,0,0}, zloc{0,0,0,0}, msb{0,0,0,0};

  // pipelined uncached slab read: 12 batches x 2 chunks x 2 dwordx4
#define ISSUE_BATCH(slot, j) do { \
    const unsigned* a0_ = pbase + (2 * (j)) * CHS;     \
    const unsigned* a1_ = pbase + (2 * (j) + 1) * CHS; \
    uld16(&bufs[slot][0], a0_); uld16(&bufs[slot][1], a0_ + 4); \
    uld16(&bufs[slot][2], a1_); uld16(&bufs[slot][3], a1_ + 4); \
  } while (0)

  for (int s = 0; s < T_STEPS; ++s) {
    // ---------- phase A: hid = y @ W_hid^T, z update ----------
    f32x4 h0{0,0,0,0}, h1{0,0,0,0}, h2{0,0,0,0};
    {
      const unsigned* pbase = Y + rtl;
      uint32x4 bufs[3][4];
      ISSUE_BATCH(0, 0);
      ISSUE_BATCH(1, 1);
#pragma unroll
      for (int j = 0; j < 12; ++j) {
        if (j < 10) ISSUE_BATCH((j + 2) % 3, j + 2);
        if (j < 10) { WAITV(8); } else if (j == 10) { WAITV(4); } else { WAITV(0); }
        const int sl = j % 3;
        bf16x8 ah, al;
        unpack8(bufs[sl][0], bufs[sl][1], &ah, &al);
        {
          bf16x8 b0 = LDSB(0 * 24 + 2 * j);
          bf16x8 b1 = LDSB(1 * 24 + 2 * j);
          bf16x8 b2 = LDSB(2 * 24 + 2 * j);
          h0 = MFMA16(ah, b0, h0); h0 = MFMA16(al, b0, h0);
          h1 = MFMA16(ah, b1, h1); h1 = MFMA16(al, b1, h1);
          h2 = MFMA16(ah, b2, h2); h2 = MFMA16(al, b2, h2);
        }
        unpack8(bufs[sl][2], bufs[sl][3], &ah, &al);
        {
          bf16x8 b0 = LDSB(0 * 24 + 2 * j + 1);
          bf16x8 b1 = LDSB(1 * 24 + 2 * j + 1);
          bf16x8 b2 = LDSB(2 * 24 + 2 * j + 1);
          h0 = MFMA16(ah, b0, h0); h0 = MFMA16(al, b0, h0);
          h1 = MFMA16(ah, b1, h1); h1 = MFMA16(al, b1, h1);
          h2 = MFMA16(ah, b2, h2); h2 = MFMA16(al, b2, h2);
        }
      }
    }
#pragma unroll
    for (int i = 0; i < 4; ++i) {
      float a1 = fsig(ai0[i] + h0[i] + c1);          // ms_dt_bar
      float a2 = fsig(ai1[i] + h1[i] + c2);          // ms_dt
      float gg = ftanh(ai3[i] + h2[i] + cy);
      float zn = (1.0f - a2) * zloc[i] + a2 * gg;
      zloc[i] = zn;
      msb[i] = a1;
      AS32(zs + (r16b + i) * 8, packf(zn));
    }
    __syncthreads();                       // drains vmcnt: stores visible
    if (tid == 0) AS32(&gfA[c * 16], (unsigned)(s + 1));

    // overlap: input projection for step s+1 (cached)
    f32x4 ni0{0,0,0,0}, ni1{0,0,0,0}, ni2{0,0,0,0}, ni3{0,0,0,0};
    if (s + 1 < T_STEPS) {
      const float* xp = x + ((size_t)(s + 1) * BATCH + rowA) * NINP;
#pragma unroll
      for (int kt = 0; kt < KI; ++kt) {
        bf16x8 ah, al;
        split8(xp + kt * 32 + kg8, &ah, &al);
        ni0 = MFMA16(ah, LDSB(T_INP0 + 0 * 4 + kt), ni0);
        ni0 = MFMA16(al, LDSB(T_INP0 + 0 * 4 + kt), ni0);
        ni1 = MFMA16(ah, LDSB(T_INP0 + 1 * 4 + kt), ni1);
        ni1 = MFMA16(al, LDSB(T_INP0 + 1 * 4 + kt), ni1);
        ni2 = MFMA16(ah, LDSB(T_INP0 + 2 * 4 + kt), ni2);
        ni2 = MFMA16(al, LDSB(T_INP0 + 2 * 4 + kt), ni2);
        ni3 = MFMA16(ah, LDSB(T_INP0 + 3 * 4 + kt), ni3);
        ni3 = MFMA16(al, LDSB(T_INP0 + 3 * 4 + kt), ni3);
      }
    }
    // wait A: all 48 flagA >= s+1 (each flag in its own 64B line)
    if (w == 0) {
      const unsigned* fp = gfA + (l < CBLK ? l * 16 : 0);
      while (true) {
        unsigned v = AL32(fp);
        if (__all((l >= CBLK) || (v >= (unsigned)(s + 1)))) break;
        __builtin_amdgcn_s_sleep(2);
      }
    }
    __syncthreads();

    // ---------- phase B: zWz = z @ W_z^T, y update ----------
    f32x4 az0{0,0,0,0}, az1{0,0,0,0};
    {
      const unsigned* pbase = Z + rtl;
      uint32x4 bufs[3][4];
      ISSUE_BATCH(0, 0);
      ISSUE_BATCH(1, 1);
#pragma unroll
      for (int j = 0; j < 12; ++j) {
        if (j < 10) ISSUE_BATCH((j + 2) % 3, j + 2);
        if (j < 10) { WAITV(8); } else if (j == 10) { WAITV(4); } else { WAITV(0); }
        const int sl = j % 3;
        bf16x8 ah, al;
        unpack8(bufs[sl][0], bufs[sl][1], &ah, &al);
        {
          bf16x8 bb = LDSB(T_WZ0 + 2 * j);
          az0 = MFMA16(ah, bb, az0); az0 = MFMA16(al, bb, az0);
        }
        unpack8(bufs[sl][2], bufs[sl][3], &ah, &al);
        {
          bf16x8 bb = LDSB(T_WZ0 + 2 * j + 1);
          az1 = MFMA16(ah, bb, az1); az1 = MFMA16(al, bb, az1);
        }
      }
    }
#pragma unroll
    for (int i = 0; i < 4; ++i) {
      float tt = ftanh(az0[i] + az1[i] + ai2[i] + cz);
      float yn = (1.0f - msb[i]) * yloc[i] + msb[i] * tt;
      yloc[i] = yn;
      AS32(ys + (r16b + i) * 8, packf(yn));
    }
    __syncthreads();
    if (tid == 0) AS32(&gfB[c * 16], (unsigned)(s + 1));
    if (w == 0) {
      const unsigned* fp = gfB + (l < CBLK ? l * 16 : 0);
      while (true) {
        unsigned v = AL32(fp);
        if (__all((l >= CBLK) || (v >= (unsigned)(s + 1)))) break;
        __builtin_amdgcn_s_sleep(2);
      }
    }
    __syncthreads();

    ai0 = ni0; ai1 = ni1; ai2 = ni2; ai3 = ni3;
  }

  // ---------- epilogue: out = y @ W_cls^T + b_cls (blocks c<8) ----------
  if (c < 8) {
    f32x4 ao0{0,0,0,0}, ao1{0,0,0,0};
    const unsigned* pbase = Y + rtl;
    for (int kt = 0; kt < KH; kt += 2) {
      uint32x4 q0, q1, q2, q3;
      uld16(&q0, pbase + kt * CHS);
      uld16(&q1, pbase + kt * CHS + 4);
      uld16(&q2, pbase + (kt + 1) * CHS);
      uld16(&q3, pbase + (kt + 1) * CHS + 4);
      bf16x8 bh0, bl0, bh1, bl1;
      split8(W_cls + (size_t)(colbase + lc) * NHID + kt * 32 + kg8, &bh0, &bl0);
      split8(W_cls + (size_t)(colbase + lc) * NHID + (kt + 1) * 32 + kg8, &bh1, &bl1);
      WAITV(0);
      bf16x8 ah, al;
      unpack8(q0, q1, &ah, &al);
      ao0 = MFMA16(ah, bh0, ao0); ao0 = MFMA16(al, bh0, ao0);
      unpack8(q2, q3, &ah, &al);
      ao1 = MFMA16(ah, bh1, ao1); ao1 = MFMA16(al, bh1, ao1);
    }
    float bc = b_cls[colbase + lc];
#pragma unroll
    for (int i = 0; i < 4; ++i)
      out[(size_t)(rowD + i) * NOUT + colbase + lc] = ao0[i] + ao1[i] + bc;
  }
}

extern "C" void kernel_launch(void* const* d_in, const int* in_sizes, int n_in,
                              void* d_out, int out_size, void* d_ws, size_t ws_size,
                              hipStream_t stream) {
  (void)in_sizes; (void)n_in; (void)out_size; (void)ws_size;
  const float* x     = (const float*)d_in[0];
  const float* W_inp = (const float*)d_in[1];
  const float* b_inp = (const float*)d_in[2];
  const float* W_hid = (const float*)d_in[3];
  const float* b_hid = (const float*)d_in[4];
  const float* W_z   = (const float*)d_in[5];
  const float* b_z   = (const float*)d_in[6];
  const float* W_cls = (const float*)d_in[7];
  const float* b_cls = (const float*)d_in[8];

  // workspace: Y (768KB), Z (768KB), flags (4 groups * 1536 u32 = 24KB)
  unsigned* Y = (unsigned*)d_ws;
  unsigned* Z = Y + SBUF;
  unsigned* flags = Z + SBUF;

  hipMemsetAsync(d_ws, 0, (2 * SBUF + NGRP * 1536) * sizeof(unsigned), stream);

  lem_kernel<<<dim3(NBLK), dim3(NTHR), 0, stream>>>(
      x, W_inp, b_inp, W_hid, b_hid, W_z, b_z, W_cls, b_cls,
      (float*)d_out, Y, Z, flags);
}

// Round 4
// 2274.345 us; speedup vs baseline: 5.5513x; 1.4491x over previous
//
#include <hip/hip_runtime.h>
#include <stdint.h>

// LEM recurrent net, MI355X persistent-kernel implementation, round 4.
// NGRP=4 batch groups (64 rows) x CBLK=48 column-blocks (16 cols) = 192
// blocks x 256 thr, 1 block/CU, weights pinned in LDS.
// State exchange: bf16-only (registers keep fp32; published operand bf16),
// fragment-ordered layout [kt][rt][kg][r16][e] -> a wave's MFMA A-fragment
// load is one contiguous 1KB block; uncached (sc0 sc1) dwordx4 inline-asm
// loads, 6-batch software pipeline with counted vmcnt.
// Barrier: 48 contiguous u32 flags per group-phase (plain stores, no RMW),
// wave0 polls all 48 with one coalesced load (3 lines). No wbl2/inv.

#define NINP 128
#define NHID 768
#define NOUT 128
#define T_STEPS 256
#define BATCH 256

#define NGRP 4
#define CBLK 48
#define NBLK (NGRP * CBLK)      // 192 blocks
#define NTHR 256
#define KH 24                   // K-chunks of 32 for K=768
#define KI 4                    // K-chunks for K=128

// LDS tile indices (tile = 16 cols x 32 k bf16 = 1KB, fragment-major)
#define T_INP0 72               // after 3*24 W_hid tiles
#define T_WZ0  88               // after 4*4 W_inp tiles
#define NTILES 112              // 112 KB LDS

// state layout [kt:24][rt:16][kg:4][r16:16][e:8] bf16; chunk stride (bf16):
#define CHS 8192                // 16*4*16*8
#define SBUF 196608             // bf16 elements per state buffer (384KB)

typedef short bf16x8 __attribute__((ext_vector_type(8)));
typedef float f32x4 __attribute__((ext_vector_type(4)));
typedef unsigned uint32x4 __attribute__((ext_vector_type(4)));

__device__ __forceinline__ unsigned short f2b(float f) {
  union { float f; unsigned u; } x; x.f = f;
  return (unsigned short)((x.u + 0x7fffu + ((x.u >> 16) & 1u)) >> 16);  // RNE
}
__device__ __forceinline__ float b2f(unsigned short h) {
  union { unsigned u; float f; } x; x.u = ((unsigned)h) << 16; return x.f;
}
__device__ __forceinline__ float fsig(float x) { return 1.0f / (1.0f + __expf(-x)); }
__device__ __forceinline__ float ftanh(float x) {
  float e = __expf(2.0f * x);
  return 1.0f - 2.0f / (e + 1.0f);
}

#define MFMA16(a, b, c) __builtin_amdgcn_mfma_f32_16x16x32_bf16(a, b, c, 0, 0, 0)

#define AL32(p) __hip_atomic_load((const unsigned*)(p), __ATOMIC_RELAXED, __HIP_MEMORY_SCOPE_AGENT)
#define AS32(p, v) __hip_atomic_store((unsigned*)(p), (v), __ATOMIC_RELAXED, __HIP_MEMORY_SCOPE_AGENT)
#define AS16(p, v) __hip_atomic_store((unsigned short*)(p), (v), __ATOMIC_RELAXED, __HIP_MEMORY_SCOPE_AGENT)

// uncached (device-coherent) 16B load; result valid only after s_waitcnt
__device__ __forceinline__ void uld16(uint32x4* dst, const unsigned short* addr) {
  asm volatile("global_load_dwordx4 %0, %1, off sc0 sc1"
               : "=v"(*dst) : "v"(addr));
}
#define WAITV(N) do { \
  asm volatile("s_waitcnt vmcnt(" #N ")" ::: "memory"); \
  __builtin_amdgcn_sched_barrier(0); } while (0)

// fp32 -> hi/lo bf16 fragments (x input, W_cls)
__device__ __forceinline__ void split8(const float* p, bf16x8* hi, bf16x8* lo) {
  union { bf16x8 v; unsigned short s[8]; } H, L;
#pragma unroll
  for (int e = 0; e < 8; ++e) {
    float v = p[e];
    unsigned short h = f2b(v);
    H.s[e] = h;
    L.s[e] = f2b(v - b2f(h));
  }
  *hi = H.v; *lo = L.v;
}

__global__ __launch_bounds__(NTHR, 1) void lem_kernel(
    const float* __restrict__ x,       // [T][B][NINP]
    const float* __restrict__ W_inp,   // [4*NHID][NINP]
    const float* __restrict__ b_inp,   // [4*NHID]
    const float* __restrict__ W_hid,   // [3*NHID][NHID]
    const float* __restrict__ b_hid,   // [3*NHID]
    const float* __restrict__ W_z,     // [NHID][NHID]
    const float* __restrict__ b_z,     // [NHID]
    const float* __restrict__ W_cls,   // [NOUT][NHID]
    const float* __restrict__ b_cls,   // [NOUT]
    float* __restrict__ out,           // [B][NOUT]
    unsigned short* __restrict__ Y,    // bf16 state, fragment-ordered
    unsigned short* __restrict__ Z,
    unsigned* __restrict__ flags)      // per group: flagA[48], pad, flagB[48]
{
  __shared__ unsigned short wlds[NTILES * 512];  // 112 KB

  const int tid = threadIdx.x;
  const int l   = tid & 63;
  const int w   = tid >> 6;            // wave 0..3
  const int g   = blockIdx.x / CBLK;
  const int c   = blockIdx.x % CBLK;
  const int colbase = c * 16;
  const int lc  = l & 15;
  const int kg8 = (l >> 4) * 8;

  // ---- one-time: pack weight slices into LDS (bf16, fragment-major) ----
  for (int idx = tid; idx < NTILES * 512; idx += NTHR) {
    int t = idx >> 9;
    int r = idx & 511;
    int ll = r >> 3;
    int e  = r & 7;
    int col16 = ll & 15;
    int kk = ((ll >> 4) * 8) + e;
    float v;
    if (t < T_INP0) {                      // W_hid
      int seg = t / 24, kt = t % 24;
      v = W_hid[(size_t)(seg * NHID + colbase + col16) * NHID + kt * 32 + kk];
    } else if (t < T_WZ0) {                // W_inp
      int u = t - T_INP0; int seg = u >> 2, kt = u & 3;
      v = W_inp[(size_t)(seg * NHID + colbase + col16) * NINP + kt * 32 + kk];
    } else {                               // W_z
      int kt = t - T_WZ0;
      v = W_z[(size_t)(colbase + col16) * NHID + kt * 32 + kk];
    }
    wlds[idx] = f2b(v);
  }
  __syncthreads();

#define LDSB(t) (*(const bf16x8*)&wlds[((t) << 9) + (l << 3)])

  const int col  = colbase + lc;
  const int rt   = 4 * g + w;                   // row tile (16 rows)
  const int rowA = rt * 16 + lc;                // A-fragment row
  const int rowD = rt * 16 + (l >> 4) * 4;      // D rows rowD..rowD+3
  const int rtl  = rt * 512 + (l >> 4) * 128 + lc * 8;  // per-lane load base
  const float c1 = b_inp[col] + b_hid[col];
  const float c2 = b_inp[NHID + col] + b_hid[NHID + col];
  const float cy = b_inp[3 * NHID + col] + b_hid[2 * NHID + col];
  const float cz = b_inp[2 * NHID + col] + b_z[col];
  // store addressing (fragment-ordered, bf16 units)
  const int kts = col >> 5, kgs = (col >> 3) & 3, es = col & 7;
  const int r16b = (l >> 4) * 4;
  unsigned short* zs = Z + ((kts * 16 + rt) * 4 + kgs) * 128 + es;
  unsigned short* ys = Y + ((kts * 16 + rt) * 4 + kgs) * 128 + es;
  unsigned* gfA = flags + g * 128;
  unsigned* gfB = gfA + 64;

  // input projection for step 0 (cached loads; x is read-only)
  f32x4 ai0{0,0,0,0}, ai1{0,0,0,0}, ai2{0,0,0,0}, ai3{0,0,0,0};
  {
    const float* xp0 = x + (size_t)rowA * NINP;
#pragma unroll
    for (int kt = 0; kt < KI; ++kt) {
      bf16x8 ah, al;
      split8(xp0 + kt * 32 + kg8, &ah, &al);
      ai0 = MFMA16(ah, LDSB(T_INP0 + 0 * 4 + kt), ai0);
      ai0 = MFMA16(al, LDSB(T_INP0 + 0 * 4 + kt), ai0);
      ai1 = MFMA16(ah, LDSB(T_INP0 + 1 * 4 + kt), ai1);
      ai1 = MFMA16(al, LDSB(T_INP0 + 1 * 4 + kt), ai1);
      ai2 = MFMA16(ah, LDSB(T_INP0 + 2 * 4 + kt), ai2);
      ai2 = MFMA16(al, LDSB(T_INP0 + 2 * 4 + kt), ai2);
      ai3 = MFMA16(ah, LDSB(T_INP0 + 3 * 4 + kt), ai3);
      ai3 = MFMA16(al, LDSB(T_INP0 + 3 * 4 + kt), ai3);
    }
  }

  f32x4 yloc{0,0,0,0}, zloc{0,0,0,0}, msb{0,0,0,0};

  // 6-deep pipelined slab read: 12 batches x 2 chunks x 1 dwordx4
#define ISSUE(slot, jj) do { \
    uld16(&bufs[slot][0], pbase + (2 * (jj)) * CHS); \
    uld16(&bufs[slot][1], pbase + (2 * (jj) + 1) * CHS); } while (0)

  for (int s = 0; s < T_STEPS; ++s) {
    // ---------- phase A: hid = y @ W_hid^T, z update ----------
    f32x4 h0{0,0,0,0}, h1{0,0,0,0}, h2{0,0,0,0};
    {
      const unsigned short* pbase = Y + rtl;
      uint32x4 bufs[6][2];
      ISSUE(0, 0); ISSUE(1, 1); ISSUE(2, 2); ISSUE(3, 3); ISSUE(4, 4);
#pragma unroll
      for (int j = 0; j < 12; ++j) {
        if (j <= 6) { ISSUE((j + 5) % 6, j + 5); WAITV(10); }
        else if (j == 7) { WAITV(8); }
        else if (j == 8) { WAITV(6); }
        else if (j == 9) { WAITV(4); }
        else if (j == 10) { WAITV(2); }
        else { WAITV(0); }
        const int sl = j % 6;
        bf16x8 a0 = __builtin_bit_cast(bf16x8, bufs[sl][0]);
        h0 = MFMA16(a0, LDSB(0 * 24 + 2 * j), h0);
        h1 = MFMA16(a0, LDSB(1 * 24 + 2 * j), h1);
        h2 = MFMA16(a0, LDSB(2 * 24 + 2 * j), h2);
        bf16x8 a1 = __builtin_bit_cast(bf16x8, bufs[sl][1]);
        h0 = MFMA16(a1, LDSB(0 * 24 + 2 * j + 1), h0);
        h1 = MFMA16(a1, LDSB(1 * 24 + 2 * j + 1), h1);
        h2 = MFMA16(a1, LDSB(2 * 24 + 2 * j + 1), h2);
      }
    }
#pragma unroll
    for (int i = 0; i < 4; ++i) {
      float a1 = fsig(ai0[i] + h0[i] + c1);          // ms_dt_bar
      float a2 = fsig(ai1[i] + h1[i] + c2);          // ms_dt
      float gg = ftanh(ai3[i] + h2[i] + cy);
      float zn = (1.0f - a2) * zloc[i] + a2 * gg;
      zloc[i] = zn;
      msb[i] = a1;
      AS16(zs + (r16b + i) * 8, f2b(zn));
    }
    __syncthreads();                       // drains vmcnt: stores visible
    if (tid == 0) AS32(&gfA[c], (unsigned)(s + 1));

    // overlap barrier latency: input projection for step s+1 (cached)
    f32x4 ni0{0,0,0,0}, ni1{0,0,0,0}, ni2{0,0,0,0}, ni3{0,0,0,0};
    if (s + 1 < T_STEPS) {
      const float* xp = x + ((size_t)(s + 1) * BATCH + rowA) * NINP;
#pragma unroll
      for (int kt = 0; kt < KI; ++kt) {
        bf16x8 ah, al;
        split8(xp + kt * 32 + kg8, &ah, &al);
        ni0 = MFMA16(ah, LDSB(T_INP0 + 0 * 4 + kt), ni0);
        ni0 = MFMA16(al, LDSB(T_INP0 + 0 * 4 + kt), ni0);
        ni1 = MFMA16(ah, LDSB(T_INP0 + 1 * 4 + kt), ni1);
        ni1 = MFMA16(al, LDSB(T_INP0 + 1 * 4 + kt), ni1);
        ni2 = MFMA16(ah, LDSB(T_INP0 + 2 * 4 + kt), ni2);
        ni2 = MFMA16(al, LDSB(T_INP0 + 2 * 4 + kt), ni2);
        ni3 = MFMA16(ah, LDSB(T_INP0 + 3 * 4 + kt), ni3);
        ni3 = MFMA16(al, LDSB(T_INP0 + 3 * 4 + kt), ni3);
      }
    }
    // wait A: all 48 flagA >= s+1 (one coalesced 192B load per poll)
    if (w == 0) {
      const unsigned* fp = gfA + (l < CBLK ? l : 0);
      while (true) {
        unsigned v = AL32(fp);
        if (__all((l >= CBLK) || (v >= (unsigned)(s + 1)))) break;
        __builtin_amdgcn_s_sleep(1);
      }
    }
    __syncthreads();

    // ---------- phase B: zWz = z @ W_z^T, y update ----------
    f32x4 az0{0,0,0,0}, az1{0,0,0,0};
    {
      const unsigned short* pbase = Z + rtl;
      uint32x4 bufs[6][2];
      ISSUE(0, 0); ISSUE(1, 1); ISSUE(2, 2); ISSUE(3, 3); ISSUE(4, 4);
#pragma unroll
      for (int j = 0; j < 12; ++j) {
        if (j <= 6) { ISSUE((j + 5) % 6, j + 5); WAITV(10); }
        else if (j == 7) { WAITV(8); }
        else if (j == 8) { WAITV(6); }
        else if (j == 9) { WAITV(4); }
        else if (j == 10) { WAITV(2); }
        else { WAITV(0); }
        const int sl = j % 6;
        bf16x8 a0 = __builtin_bit_cast(bf16x8, bufs[sl][0]);
        az0 = MFMA16(a0, LDSB(T_WZ0 + 2 * j), az0);
        bf16x8 a1 = __builtin_bit_cast(bf16x8, bufs[sl][1]);
        az1 = MFMA16(a1, LDSB(T_WZ0 + 2 * j + 1), az1);
      }
    }
#pragma unroll
    for (int i = 0; i < 4; ++i) {
      float tt = ftanh(az0[i] + az1[i] + ai2[i] + cz);
      float yn = (1.0f - msb[i]) * yloc[i] + msb[i] * tt;
      yloc[i] = yn;
      AS16(ys + (r16b + i) * 8, f2b(yn));
    }
    __syncthreads();
    if (tid == 0) AS32(&gfB[c], (unsigned)(s + 1));
    if (w == 0) {
      const unsigned* fp = gfB + (l < CBLK ? l : 0);
      while (true) {
        unsigned v = AL32(fp);
        if (__all((l >= CBLK) || (v >= (unsigned)(s + 1)))) break;
        __builtin_amdgcn_s_sleep(1);
      }
    }
    __syncthreads();

    ai0 = ni0; ai1 = ni1; ai2 = ni2; ai3 = ni3;
  }

  // ---------- epilogue: out = y @ W_cls^T + b_cls (blocks c<8) ----------
  if (c < 8) {
    f32x4 ao0{0,0,0,0}, ao1{0,0,0,0};
    const unsigned short* pbase = Y + rtl;
    for (int kt = 0; kt < KH; kt += 2) {
      uint32x4 q0, q1;
      uld16(&q0, pbase + kt * CHS);
      uld16(&q1, pbase + (kt + 1) * CHS);
      bf16x8 bh0, bl0, bh1, bl1;
      split8(W_cls + (size_t)(colbase + lc) * NHID + kt * 32 + kg8, &bh0, &bl0);
      split8(W_cls + (size_t)(colbase + lc) * NHID + (kt + 1) * 32 + kg8, &bh1, &bl1);
      WAITV(0);
      bf16x8 a0 = __builtin_bit_cast(bf16x8, q0);
      ao0 = MFMA16(a0, bh0, ao0); ao0 = MFMA16(a0, bl0, ao0);
      bf16x8 a1 = __builtin_bit_cast(bf16x8, q1);
      ao1 = MFMA16(a1, bh1, ao1); ao1 = MFMA16(a1, bl1, ao1);
    }
    float bc = b_cls[colbase + lc];
#pragma unroll
    for (int i = 0; i < 4; ++i)
      out[(size_t)(rowD + i) * NOUT + colbase + lc] = ao0[i] + ao1[i] + bc;
  }
}

extern "C" void kernel_launch(void* const* d_in, const int* in_sizes, int n_in,
                              void* d_out, int out_size, void* d_ws, size_t ws_size,
                              hipStream_t stream) {
  (void)in_sizes; (void)n_in; (void)out_size; (void)ws_size;
  const float* x     = (const float*)d_in[0];
  const float* W_inp = (const float*)d_in[1];
  const float* b_inp = (const float*)d_in[2];
  const float* W_hid = (const float*)d_in[3];
  const float* b_hid = (const float*)d_in[4];
  const float* W_z   = (const float*)d_in[5];
  const float* b_z   = (const float*)d_in[6];
  const float* W_cls = (const float*)d_in[7];
  const float* b_cls = (const float*)d_in[8];

  // workspace: Y (384KB), Z (384KB), flags (4 groups * 128 u32 = 2KB)
  unsigned short* Y = (unsigned short*)d_ws;
  unsigned short* Z = Y + SBUF;
  unsigned* flags = (unsigned*)((char*)d_ws + 2 * SBUF * sizeof(unsigned short));

  hipMemsetAsync(d_ws, 0, 2 * SBUF * sizeof(unsigned short) + NGRP * 128 * sizeof(unsigned), stream);

  lem_kernel<<<dim3(NBLK), dim3(NTHR), 0, stream>>>(
      x, W_inp, b_inp, W_hid, b_hid, W_z, b_z, W_cls, b_cls,
      (float*)d_out, Y, Z, flags);
}